// Round 1
// baseline (137.588 us; speedup 1.0000x reference)
//
#include <hip/hip_runtime.h>

#define NB 64
#define NS 512
#define ND 768
#define NT 4

// ---------------------------------------------------------------------------
// Kernel 1: fused embedding gather + (shared + domain) projection + log_softmax
// grid = NB*8 blocks of 256 threads. block -> batch b = blockIdx/8, s-range of 64.
// One wave per token; lane l covers d = ch*256 + 4*l + q (ch<3, q<4).
// ---------------------------------------------------------------------------
__global__ __launch_bounds__(256, 4) void logits_kernel(
    const int* __restrict__ words, const int* __restrict__ corpus,
    const float* __restrict__ embed, const float* __restrict__ sW,
    const float* __restrict__ sb, const float* __restrict__ dA,
    const float* __restrict__ db, float* __restrict__ logits)
{
  const int lane = threadIdx.x & 63;
  const int wv   = threadIdx.x >> 6;
  const int b    = blockIdx.x >> 3;
  const int sblk = (blockIdx.x & 7) * 64;
  const int c    = corpus[b];

  // Effective weight W_eff[d][t] for this block's corpus, in registers.
  float4 w[3][4];
  const float4* sW4 = (const float4*)sW;
  const float4* dA4 = (const float4*)(dA + (size_t)c * ND * NT);
#pragma unroll
  for (int ch = 0; ch < 3; ++ch) {
#pragma unroll
    for (int q = 0; q < 4; ++q) {
      const int d = ch * 256 + lane * 4 + q;
      const float4 a = sW4[d];
      const float4 e = dA4[d];
      w[ch][q] = make_float4(a.x + e.x, a.y + e.y, a.z + e.z, a.w + e.w);
    }
  }
  float4 bias;
  {
    const float4 a = *(const float4*)sb;
    const float4 e = *(const float4*)(db + c * NT);
    bias = make_float4(a.x + e.x, a.y + e.y, a.z + e.z, a.w + e.w);
  }

#pragma unroll 2
  for (int i = 0; i < 16; ++i) {
    const int s = sblk + i * 4 + wv;
    const int word = words[b * NS + s];
    const float4* x4 = (const float4*)(embed + (size_t)word * ND);
    float a0 = 0.f, a1 = 0.f, a2 = 0.f, a3 = 0.f;
#pragma unroll
    for (int ch = 0; ch < 3; ++ch) {
      const float4 xv = x4[ch * 64 + lane];
      a0 = fmaf(xv.x, w[ch][0].x, a0); a1 = fmaf(xv.x, w[ch][0].y, a1);
      a2 = fmaf(xv.x, w[ch][0].z, a2); a3 = fmaf(xv.x, w[ch][0].w, a3);
      a0 = fmaf(xv.y, w[ch][1].x, a0); a1 = fmaf(xv.y, w[ch][1].y, a1);
      a2 = fmaf(xv.y, w[ch][1].z, a2); a3 = fmaf(xv.y, w[ch][1].w, a3);
      a0 = fmaf(xv.z, w[ch][2].x, a0); a1 = fmaf(xv.z, w[ch][2].y, a1);
      a2 = fmaf(xv.z, w[ch][2].z, a2); a3 = fmaf(xv.z, w[ch][2].w, a3);
      a0 = fmaf(xv.w, w[ch][3].x, a0); a1 = fmaf(xv.w, w[ch][3].y, a1);
      a2 = fmaf(xv.w, w[ch][3].z, a2); a3 = fmaf(xv.w, w[ch][3].w, a3);
    }
    // full-wave butterfly reduce (all lanes end with totals)
#pragma unroll
    for (int off = 32; off; off >>= 1) {
      a0 += __shfl_xor(a0, off);
      a1 += __shfl_xor(a1, off);
      a2 += __shfl_xor(a2, off);
      a3 += __shfl_xor(a3, off);
    }
    if (lane == 0) {
      a0 += bias.x; a1 += bias.y; a2 += bias.z; a3 += bias.w;
      const float m = fmaxf(fmaxf(a0, a1), fmaxf(a2, a3));
      const float sum = __expf(a0 - m) + __expf(a1 - m) + __expf(a2 - m) + __expf(a3 - m);
      const float lse = m + __logf(sum);
      ((float4*)logits)[b * NS + s] = make_float4(a0 - lse, a1 - lse, a2 - lse, a3 - lse);
    }
  }
}

// ---------------------------------------------------------------------------
// Kernel 2: CRF forward (normalizer) + gold score, fused.
// 4 blocks x 64 threads; 4 lanes per batch (lane j owns state j).
// Replicated alpha in XOR-slot order: A_k = alpha[j^k], TR_k = trans[j^k][j].
// ---------------------------------------------------------------------------
__global__ __launch_bounds__(64) void crf_kernel(
    const int* __restrict__ words, const int* __restrict__ target,
    const float* __restrict__ trans, const float* __restrict__ start_s,
    const float* __restrict__ end_s, const float* __restrict__ logits,
    float* __restrict__ out)
{
  const int lane = threadIdx.x;
  const int j = lane & 3;
  const int g = lane >> 2;
  const int b = blockIdx.x * 16 + g;

  const float TR0 = trans[((j ^ 0) << 2) | j];
  const float TR1 = trans[((j ^ 1) << 2) | j];
  const float TR2 = trans[((j ^ 2) << 2) | j];
  const float TR3 = trans[((j ^ 3) << 2) | j];
  const float E0 = end_s[j ^ 0], E1 = end_s[j ^ 1];
  const float E2 = end_s[j ^ 2], E3 = end_s[j ^ 3];
  const float startj = start_s[j];

  const float* lg = logits + (size_t)b * NS * NT;
  const int* wb = words + b * NS;
  const int* tb = target + b * NS;

  // s = 0
  const float l0 = lg[j];
  const int t0 = tb[0];
  const bool m0 = (wb[0] != 0);
  float v = l0 + startj;
  float A0 = v;
  float A1 = __shfl_xor(v, 1, 4);
  float A2 = __shfl_xor(v, 2, 4);
  float A3 = __shfl_xor(A1, 2, 4);

  float emit_acc = (m0 && (j == t0)) ? l0 : 0.f;
  float tr_acc = 0.f;
  int cnt = m0 ? 1 : 0;
  int pt = t0;

#pragma unroll 4
  for (int s = 1; s < NS; ++s) {
    const float ls = lg[s * 4 + j];
    const int ws = wb[s];
    const int ts = tb[s];
    const bool mk = (ws != 0);

    const float t0v = A0 + TR0, t1v = A1 + TR1, t2v = A2 + TR2, t3v = A3 + TR3;
    const float mx = fmaxf(fmaxf(t0v, t1v), fmaxf(t2v, t3v));
    const float sum = __expf(t0v - mx) + __expf(t1v - mx) +
                      __expf(t2v - mx) + __expf(t3v - mx);
    const float nv = ls + mx + __logf(sum);
    const float n1 = __shfl_xor(nv, 1, 4);
    const float n2 = __shfl_xor(nv, 2, 4);
    const float n3 = __shfl_xor(n1, 2, 4);
    A0 = mk ? nv : A0;
    A1 = mk ? n1 : A1;
    A2 = mk ? n2 : A2;
    A3 = mk ? n3 : A3;

    // gold terms
    emit_acc += (mk && (j == ts)) ? ls : 0.f;
    const int k = pt ^ ts;  // lane ts: TR_k = trans[ts^k][ts] = trans[pt][ts]
    const float sel = (k == 0) ? TR0 : (k == 1) ? TR1 : (k == 2) ? TR2 : TR3;
    const float trv = __shfl(sel, ts, 4);
    tr_acc += mk ? trv : 0.f;
    cnt += mk ? 1 : 0;
    pt = ts;
  }

  // normalizer = LSE_j(alpha[j] + end[j]) — replicated slots make this local
  const float z0 = A0 + E0, z1 = A1 + E1, z2 = A2 + E2, z3 = A3 + E3;
  const float mz = fmaxf(fmaxf(z0, z1), fmaxf(z2, z3));
  const float norm = mz + __logf(__expf(z0 - mz) + __expf(z1 - mz) +
                                 __expf(z2 - mz) + __expf(z3 - mz));

  // emit is distributed across the 4 lanes; tr/cnt are replicated
  float em = emit_acc;
  em += __shfl_xor(em, 1, 4);
  em += __shfl_xor(em, 2, 4);

  if (j == 0) {
    const int last = (cnt - 1) > 0 ? (cnt - 1) : 0;
    const float gold = em + tr_acc + start_s[t0] + end_s[tb[last]];
    out[b] = norm - gold;
  }
}

extern "C" void kernel_launch(void* const* d_in, const int* in_sizes, int n_in,
                              void* d_out, int out_size, void* d_ws, size_t ws_size,
                              hipStream_t stream) {
  const int*   words   = (const int*)d_in[0];
  const int*   target  = (const int*)d_in[1];
  const int*   corpus  = (const int*)d_in[2];
  const float* embed   = (const float*)d_in[3];
  const float* sW      = (const float*)d_in[4];
  const float* sb      = (const float*)d_in[5];
  const float* dA      = (const float*)d_in[6];
  const float* db      = (const float*)d_in[7];
  const float* trans   = (const float*)d_in[8];
  const float* start_s = (const float*)d_in[9];
  const float* end_s   = (const float*)d_in[10];
  float* out = (float*)d_out;
  float* logits = (float*)d_ws;  // NB*NS*NT floats = 512 KB

  logits_kernel<<<NB * 8, 256, 0, stream>>>(words, corpus, embed, sW, sb, dA, db, logits);
  crf_kernel<<<4, 64, 0, stream>>>(words, target, trans, start_s, end_s, logits, out);
}

// Round 2
// 36.576 us; speedup vs baseline: 3.7617x; 3.7617x over previous
//
#include <hip/hip_runtime.h>

#define NB 64
#define NS 512
#define ND 768
#define NT 4
#define NEG (-1e30f)

// ---------------------------------------------------------------------------
// Kernel 1: fused embedding gather + (shared + domain) projection + log_softmax
// grid = NB*8 blocks of 256 threads. block -> batch b = blockIdx/8, s-range of 64.
// One wave per token; lane l covers d = ch*256 + 4*l + q (ch<3, q<4).
// ---------------------------------------------------------------------------
__global__ __launch_bounds__(256, 4) void logits_kernel(
    const int* __restrict__ words, const int* __restrict__ corpus,
    const float* __restrict__ embed, const float* __restrict__ sW,
    const float* __restrict__ sb, const float* __restrict__ dA,
    const float* __restrict__ db, float* __restrict__ logits)
{
  const int lane = threadIdx.x & 63;
  const int wv   = threadIdx.x >> 6;
  const int b    = blockIdx.x >> 3;
  const int sblk = (blockIdx.x & 7) * 64;
  const int c    = corpus[b];

  float4 w[3][4];
  const float4* sW4 = (const float4*)sW;
  const float4* dA4 = (const float4*)(dA + (size_t)c * ND * NT);
#pragma unroll
  for (int ch = 0; ch < 3; ++ch) {
#pragma unroll
    for (int q = 0; q < 4; ++q) {
      const int d = ch * 256 + lane * 4 + q;
      const float4 a = sW4[d];
      const float4 e = dA4[d];
      w[ch][q] = make_float4(a.x + e.x, a.y + e.y, a.z + e.z, a.w + e.w);
    }
  }
  float4 bias;
  {
    const float4 a = *(const float4*)sb;
    const float4 e = *(const float4*)(db + c * NT);
    bias = make_float4(a.x + e.x, a.y + e.y, a.z + e.z, a.w + e.w);
  }

#pragma unroll 2
  for (int i = 0; i < 16; ++i) {
    const int s = sblk + i * 4 + wv;
    const int word = words[b * NS + s];
    const float4* x4 = (const float4*)(embed + (size_t)word * ND);
    float a0 = 0.f, a1 = 0.f, a2 = 0.f, a3 = 0.f;
#pragma unroll
    for (int ch = 0; ch < 3; ++ch) {
      const float4 xv = x4[ch * 64 + lane];
      a0 = fmaf(xv.x, w[ch][0].x, a0); a1 = fmaf(xv.x, w[ch][0].y, a1);
      a2 = fmaf(xv.x, w[ch][0].z, a2); a3 = fmaf(xv.x, w[ch][0].w, a3);
      a0 = fmaf(xv.y, w[ch][1].x, a0); a1 = fmaf(xv.y, w[ch][1].y, a1);
      a2 = fmaf(xv.y, w[ch][1].z, a2); a3 = fmaf(xv.y, w[ch][1].w, a3);
      a0 = fmaf(xv.z, w[ch][2].x, a0); a1 = fmaf(xv.z, w[ch][2].y, a1);
      a2 = fmaf(xv.z, w[ch][2].z, a2); a3 = fmaf(xv.z, w[ch][2].w, a3);
      a0 = fmaf(xv.w, w[ch][3].x, a0); a1 = fmaf(xv.w, w[ch][3].y, a1);
      a2 = fmaf(xv.w, w[ch][3].z, a2); a3 = fmaf(xv.w, w[ch][3].w, a3);
    }
#pragma unroll
    for (int off = 32; off; off >>= 1) {
      a0 += __shfl_xor(a0, off);
      a1 += __shfl_xor(a1, off);
      a2 += __shfl_xor(a2, off);
      a3 += __shfl_xor(a3, off);
    }
    if (lane == 0) {
      a0 += bias.x; a1 += bias.y; a2 += bias.z; a3 += bias.w;
      const float m = fmaxf(fmaxf(a0, a1), fmaxf(a2, a3));
      const float sum = __expf(a0 - m) + __expf(a1 - m) + __expf(a2 - m) + __expf(a3 - m);
      const float lse = m + __logf(sum);
      ((float4*)logits)[b * NS + s] = make_float4(a0 - lse, a1 - lse, a2 - lse, a3 - lse);
    }
  }
}

// ---------------------------------------------------------------------------
// Kernel 2: CRF via chunk-parallel log-semiring scan + fused gold score.
// 64 blocks (one per batch) x 256 threads = 64 chunks x 4 basis rows.
// Phase A: thread (c,a) computes row a of the composed 4x4 matrix for
//          chunk c (8 steps, masked steps skipped = identity).
// Phase B: 6-level pairwise tree composition in LDS, then normalizer.
// Gold:    block-wide reduction, 2 positions per thread.
// ---------------------------------------------------------------------------
__global__ __launch_bounds__(256) void crf_kernel(
    const int* __restrict__ words, const int* __restrict__ target,
    const float* __restrict__ trans, const float* __restrict__ start_s,
    const float* __restrict__ end_s, const float* __restrict__ logits,
    float* __restrict__ out)
{
  const int tid = threadIdx.x;
  const int b = blockIdx.x;
  const int c = tid >> 2;   // chunk 0..63
  const int a = tid & 3;    // basis row

  __shared__ float bufA[64][16];
  __shared__ float bufB[32][16];
  __shared__ float wg[4];
  __shared__ int   wc[4];

  const float* lg = logits + (size_t)b * NS * NT;
  const int* wb = words + b * NS;
  const int* tb = target + b * NS;

  // ---- gold partials: positions 2*tid, 2*tid+1 ----
  float gp = 0.f; int cp = 0;
#pragma unroll
  for (int q = 0; q < 2; ++q) {
    const int s = tid * 2 + q;
    if (wb[s] != 0) {
      const int t = tb[s];
      gp += lg[s * 4 + t];                       // emit
      if (s > 0) gp += trans[tb[s - 1] * 4 + t]; // transition (global: L1, rule #20)
      ++cp;
    }
  }
#pragma unroll
  for (int off = 32; off; off >>= 1) {
    gp += __shfl_xor(gp, off);
    cp += __shfl_xor(cp, off);
  }
  if ((tid & 63) == 0) { wg[tid >> 6] = gp; wc[tid >> 6] = cp; }

  // ---- phase A: chunk recursion ----
  float T[4][4];
#pragma unroll
  for (int i = 0; i < 4; ++i)
#pragma unroll
    for (int j = 0; j < 4; ++j) T[i][j] = trans[i * 4 + j];

  const int s_beg = 1 + c * 8;   // chunks cover s = 1..511
  float4 lv[8]; int wm[8];
#pragma unroll
  for (int q = 0; q < 8; ++q) {
    const int s = s_beg + q;
    const bool in = s < NS;
    wm[q] = in ? wb[s] : 0;
    lv[q] = in ? *(const float4*)(lg + s * 4) : make_float4(0.f, 0.f, 0.f, 0.f);
  }

  float v0 = (a == 0) ? 0.f : NEG;
  float v1 = (a == 1) ? 0.f : NEG;
  float v2 = (a == 2) ? 0.f : NEG;
  float v3 = (a == 3) ? 0.f : NEG;
#pragma unroll
  for (int q = 0; q < 8; ++q) {
    if (wm[q] != 0) {
      const float4 l = lv[q];
      float t0, t1, t2, t3, m, sm;
      float n0, n1, n2, n3;
      t0 = v0 + T[0][0]; t1 = v1 + T[1][0]; t2 = v2 + T[2][0]; t3 = v3 + T[3][0];
      m = fmaxf(fmaxf(t0, t1), fmaxf(t2, t3));
      sm = __expf(t0 - m) + __expf(t1 - m) + __expf(t2 - m) + __expf(t3 - m);
      n0 = m + __logf(sm) + l.x;
      t0 = v0 + T[0][1]; t1 = v1 + T[1][1]; t2 = v2 + T[2][1]; t3 = v3 + T[3][1];
      m = fmaxf(fmaxf(t0, t1), fmaxf(t2, t3));
      sm = __expf(t0 - m) + __expf(t1 - m) + __expf(t2 - m) + __expf(t3 - m);
      n1 = m + __logf(sm) + l.y;
      t0 = v0 + T[0][2]; t1 = v1 + T[1][2]; t2 = v2 + T[2][2]; t3 = v3 + T[3][2];
      m = fmaxf(fmaxf(t0, t1), fmaxf(t2, t3));
      sm = __expf(t0 - m) + __expf(t1 - m) + __expf(t2 - m) + __expf(t3 - m);
      n2 = m + __logf(sm) + l.z;
      t0 = v0 + T[0][3]; t1 = v1 + T[1][3]; t2 = v2 + T[2][3]; t3 = v3 + T[3][3];
      m = fmaxf(fmaxf(t0, t1), fmaxf(t2, t3));
      sm = __expf(t0 - m) + __expf(t1 - m) + __expf(t2 - m) + __expf(t3 - m);
      n3 = m + __logf(sm) + l.w;
      v0 = n0; v1 = n1; v2 = n2; v3 = n3;
    }
  }
  bufA[c][a * 4 + 0] = v0;
  bufA[c][a * 4 + 1] = v1;
  bufA[c][a * 4 + 2] = v2;
  bufA[c][a * 4 + 3] = v3;

  // ---- phase B: pairwise tree composition (6 levels) ----
  float* src = &bufA[0][0];
  float* dst = &bufB[0][0];
  for (int n = 64; n > 1; n >>= 1) {
    const int entries = (n >> 1) * 16;
    __syncthreads();
    for (int e = tid; e < entries; e += 256) {
      const int p = e >> 4;
      const int aa = (e >> 2) & 3;
      const int jj = e & 3;
      const float* C1 = src + (2 * p) * 16;
      const float* C2 = src + (2 * p + 1) * 16;
      const float t0 = C1[aa * 4 + 0] + C2[0 * 4 + jj];
      const float t1 = C1[aa * 4 + 1] + C2[1 * 4 + jj];
      const float t2 = C1[aa * 4 + 2] + C2[2 * 4 + jj];
      const float t3 = C1[aa * 4 + 3] + C2[3 * 4 + jj];
      const float m = fmaxf(fmaxf(t0, t1), fmaxf(t2, t3));
      dst[p * 16 + aa * 4 + jj] =
          m + __logf(__expf(t0 - m) + __expf(t1 - m) + __expf(t2 - m) + __expf(t3 - m));
    }
    float* tmp = src; src = dst; dst = tmp;
  }
  __syncthreads();
  // after 6 iterations the final matrix is back in bufA[0]

  if (tid == 0) {
    const float* C = &bufA[0][0];
    const float4 l0 = *(const float4*)lg;
    const float a0 = l0.x + start_s[0];
    const float a1 = l0.y + start_s[1];
    const float a2 = l0.z + start_s[2];
    const float a3 = l0.w + start_s[3];
    float af[4];
#pragma unroll
    for (int j = 0; j < 4; ++j) {
      const float t0 = a0 + C[0 * 4 + j];
      const float t1 = a1 + C[1 * 4 + j];
      const float t2 = a2 + C[2 * 4 + j];
      const float t3 = a3 + C[3 * 4 + j];
      const float m = fmaxf(fmaxf(t0, t1), fmaxf(t2, t3));
      af[j] = m + __logf(__expf(t0 - m) + __expf(t1 - m) + __expf(t2 - m) + __expf(t3 - m));
    }
    const float z0 = af[0] + end_s[0], z1 = af[1] + end_s[1];
    const float z2 = af[2] + end_s[2], z3 = af[3] + end_s[3];
    const float mz = fmaxf(fmaxf(z0, z1), fmaxf(z2, z3));
    const float norm = mz + __logf(__expf(z0 - mz) + __expf(z1 - mz) +
                                   __expf(z2 - mz) + __expf(z3 - mz));

    float gold = wg[0] + wg[1] + wg[2] + wg[3];
    const int cnt = wc[0] + wc[1] + wc[2] + wc[3];
    const int last = (cnt - 1) > 0 ? (cnt - 1) : 0;
    gold += start_s[tb[0]] + end_s[tb[last]];
    out[b] = norm - gold;
  }
}

extern "C" void kernel_launch(void* const* d_in, const int* in_sizes, int n_in,
                              void* d_out, int out_size, void* d_ws, size_t ws_size,
                              hipStream_t stream) {
  const int*   words   = (const int*)d_in[0];
  const int*   target  = (const int*)d_in[1];
  const int*   corpus  = (const int*)d_in[2];
  const float* embed   = (const float*)d_in[3];
  const float* sW      = (const float*)d_in[4];
  const float* sb      = (const float*)d_in[5];
  const float* dA      = (const float*)d_in[6];
  const float* db      = (const float*)d_in[7];
  const float* trans   = (const float*)d_in[8];
  const float* start_s = (const float*)d_in[9];
  const float* end_s   = (const float*)d_in[10];
  float* out = (float*)d_out;
  float* logits = (float*)d_ws;  // NB*NS*NT floats = 512 KB

  logits_kernel<<<NB * 8, 256, 0, stream>>>(words, corpus, embed, sW, sb, dA, db, logits);
  crf_kernel<<<NB, 256, 0, stream>>>(words, target, trans, start_s, end_s, logits, out);
}